// Round 2
// baseline (2325.829 us; speedup 1.0000x reference)
//
#include <hip/hip_runtime.h>
#include <hip/hip_bf16.h>

#define BB 128
#define TT 512
#define EE 128
#define HH 256
#define MM 1024
#define CC 5

typedef _Float16 h2 __attribute__((ext_vector_type(2)));
typedef __fp16 f16x2 __attribute__((ext_vector_type(2)));
typedef __fp16 f16x8 __attribute__((ext_vector_type(8)));
typedef float  f32x4 __attribute__((ext_vector_type(4)));

__device__ inline h2 mkh2(float a, float b) {
    return __builtin_bit_cast(h2, __builtin_amdgcn_cvt_pkrtz(a, b));
}

// pack 8 f32 -> 8 f16 (one MFMA operand fragment)
__device__ inline f16x8 pack8(float4 lo, float4 hi) {
    union { f16x2 h[4]; f16x8 v; } u;
    u.h[0] = __builtin_amdgcn_cvt_pkrtz(lo.x, lo.y);
    u.h[1] = __builtin_amdgcn_cvt_pkrtz(lo.z, lo.w);
    u.h[2] = __builtin_amdgcn_cvt_pkrtz(hi.x, hi.y);
    u.h[3] = __builtin_amdgcn_cvt_pkrtz(hi.z, hi.w);
    return u.v;
}

__device__ inline float fast_tanh(float x) {
    float e = __expf(2.0f * x);
    return 1.0f - 2.0f / (e + 1.0f);
}

// ---------------------------------------------------------------------------
// K1 (MFMA GEMM): u[tok][ch] = bias[ch] + emb[x[tok]] @ W_ih^T, f16 out.
// (unchanged — verified)
// Layouts (m89/m120-verified): A[m=lane&15][k=quad*8+j],
// B[k=quad*8+j][n=lane&15], D col=lane&15 row=quad*4+reg.
// ---------------------------------------------------------------------------
__global__ __launch_bounds__(256, 2)
void k_embed(const int* __restrict__ x,
             const float* __restrict__ emb, const float* __restrict__ W_ih,
             const float* __restrict__ b_ih, const float* __restrict__ b_hh,
             _Float16* __restrict__ u)
{
    const int tb   = blockIdx.x;        // 32-token tile
    const int tid  = threadIdx.x;
    const int wv   = tid >> 6;
    const int lane = tid & 63;
    const int l15  = lane & 15;
    const int quad = lane >> 4;

    __shared__ __align__(16) char ldsA[32 * 256];   // 8KB f16 A-stage
    __shared__ __align__(16) char ldsO[32 * 512];   // 16KB f16 output tile

    f16x8 bf[4][4];
    float bias[4];
    #pragma unroll
    for (int ct = 0; ct < 4; ++ct) {
        const int n = 64 * wv + 16 * ct + l15;
        const float* wp = W_ih + (size_t)n * EE;
        #pragma unroll
        for (int kc = 0; kc < 4; ++kc) {
            const float4* p = (const float4*)(wp + 32 * kc + 8 * quad);
            bf[ct][kc] = pack8(p[0], p[1]);
        }
        bias[ct] = b_ih[n] + b_hh[n];
    }

    {
        const int r = tid >> 3;          // row 0..31
        const int s = tid & 7;           // 16-float segment
        const int tok = x[tb * 32 + r];
        const float4* ep = (const float4*)(emb + (size_t)tok * EE + 16 * s);
        float4 a = ep[0], b = ep[1], c = ep[2], d = ep[3];
        *(f16x8*)(ldsA + r * 256 + 32 * s)      = pack8(a, b);
        *(f16x8*)(ldsA + r * 256 + 32 * s + 16) = pack8(c, d);
    }
    __syncthreads();

    f32x4 acc[2][4];
    #pragma unroll
    for (int rt = 0; rt < 2; ++rt)
        #pragma unroll
        for (int ct = 0; ct < 4; ++ct)
            acc[rt][ct] = (f32x4){bias[ct], bias[ct], bias[ct], bias[ct]};

    #pragma unroll
    for (int kc = 0; kc < 4; ++kc) {
        const int ko = (32 * kc + 8 * quad) * 2;
        f16x8 a0 = *(const f16x8*)(ldsA + (l15)      * 256 + ko);
        f16x8 a1 = *(const f16x8*)(ldsA + (16 + l15) * 256 + ko);
        #pragma unroll
        for (int ct = 0; ct < 4; ++ct) {
            acc[0][ct] = __builtin_amdgcn_mfma_f32_16x16x32_f16(a0, bf[ct][kc], acc[0][ct], 0, 0, 0);
            acc[1][ct] = __builtin_amdgcn_mfma_f32_16x16x32_f16(a1, bf[ct][kc], acc[1][ct], 0, 0, 0);
        }
    }

    #pragma unroll
    for (int rt = 0; rt < 2; ++rt) {
        #pragma unroll
        for (int ct = 0; ct < 4; ++ct) {
            const int chb = (64 * wv + 16 * ct + l15) * 2;
            #pragma unroll
            for (int rg = 0; rg < 4; ++rg) {
                const int tok = 16 * rt + 4 * quad + rg;
                *(_Float16*)(ldsO + tok * 512 + chb) = (_Float16)acc[rt][ct][rg];
            }
        }
    }
    __syncthreads();

    {
        char* dst = (char*)u + (size_t)tb * 16384 + tid * 64;
        const char* src = ldsO + tid * 64;
        #pragma unroll
        for (int q = 0; q < 4; ++q)
            *(float4*)(dst + 16 * q) = *(const float4*)(src + 16 * q);
    }
}

// ---------------------------------------------------------------------------
// K2 (R8): BATCHED MFMA scan + fused MLP head. 8 blocks x 512 threads; each
// block owns 16 batch rows and steps H[16][256] = tanh(U_t + H @ W_hh^T)
// through the matrix pipe: 16 MFMAs (16x16x32 f16) per wave per step, W_hh
// B-frags resident in registers. Per-step critical path: 8 swizzled
// ds_read_b128 (A) -> 16 MFMA (2 interleaved 8-chains) -> 8 tanh+mask ->
// 8 f16 LDS stores -> 1 barrier (~450 cyc vs 1464 for the per-batch VALU
// scan). U_t gathered from global (8 ushort/lane), prefetched 2 steps ahead.
// H tile XOR-swizzled (byte ^= (row&7)<<4) on write AND read -> stride-512B
// column reads are conflict-free (G4). Rows masked t >= T-len (exact 0 before
// start). Block starts at t0 = T - max(len of its 16 rows).
// Head fused (no hn workspace; ws stays exactly 32MiB): W0 layer via same
// MFMA path (B-frags streamed from W0 global), W1 + log_softmax on VALU.
// ---------------------------------------------------------------------------
__global__ __launch_bounds__(512, 1)
void k_rnn_head(const int* __restrict__ lengths, const float* __restrict__ W_hh,
                const _Float16* __restrict__ u,
                const float* __restrict__ W0, const float* __restrict__ b0,
                const float* __restrict__ W1, const float* __restrict__ b1,
                float* __restrict__ out)
{
    const int bB   = blockIdx.x * 16;     // first batch row of this block
    const int tid  = threadIdx.x;
    const int wv   = tid >> 6;            // wave 0..7 -> channels [32wv,32wv+32)
    const int lane = tid & 63;
    const int l15  = lane & 15;
    const int quad = lane >> 4;

    __shared__ __align__(16) char ldsH[2][16 * 512];   // 2 x 8KB h[16][256] f16
    __shared__ __align__(16) char ldsH1[16 * 2048];    // 32KB relu(h@W0^T) f16
    __shared__ int slen[16];

    if (tid < 16) slen[tid] = lengths[bB + tid];

    // W_hh B-frags: bf[ct][kc], n = 32*wv + 16*ct + l15, k = 32*kc+8*quad+j
    f16x8 bf[2][8];
    #pragma unroll
    for (int ct = 0; ct < 2; ++ct) {
        const int n = 32 * wv + 16 * ct + l15;
        const float* wp = W_hh + (size_t)n * HH;
        #pragma unroll
        for (int kc = 0; kc < 8; ++kc) {
            const float4* p = (const float4*)(wp + 32 * kc + 8 * quad);
            bf[ct][kc] = pack8(p[0], p[1]);
        }
    }

    // zero h buffer 0 (512 threads x 16B = 8KB)
    ((float4*)ldsH[0])[tid] = (float4){0.f, 0.f, 0.f, 0.f};
    __syncthreads();

    int maxlen = 0;
    #pragma unroll
    for (int i = 0; i < 16; ++i) maxlen = max(maxlen, slen[i]);
    int start[4];
    #pragma unroll
    for (int rg = 0; rg < 4; ++rg) {
        int L = slen[quad * 4 + rg];
        start[rg] = (L >= TT) ? 0 : (TT - L);
    }
    const int t0 = TT - maxlen;

    // u gather bases: row m = quad*4+rg, channel base 32*wv + l15 (ct adds 16)
    const _Float16* ub[4];
    #pragma unroll
    for (int rg = 0; rg < 4; ++rg)
        ub[rg] = u + (size_t)(bB + quad * 4 + rg) * TT * HH + 32 * wv + l15;

    // 2-deep u prefetch
    _Float16 uv[2][8];
    {
        const int ta = (t0 < TT - 1) ? t0 : (TT - 1);
        const int tb2 = (t0 + 1 < TT - 1) ? (t0 + 1) : (TT - 1);
        #pragma unroll
        for (int ct = 0; ct < 2; ++ct)
            #pragma unroll
            for (int rg = 0; rg < 4; ++rg) {
                uv[0][ct * 4 + rg] = ub[rg][(size_t)ta  * HH + ct * 16];
                uv[1][ct * 4 + rg] = ub[rg][(size_t)tb2 * HH + ct * 16];
            }
    }

    const int rbase = l15 * 512;          // A row = batch = l15
    const int rswz  = (l15 & 7) << 4;     // G4 XOR swizzle
    const int cbase = quad * 16;          // byte offset of 8-f16 k-slice

    int p = 0, sel = 0;
    for (int t = t0; t < TT; ++t) {
        // A-frags from ldsH[p] (swizzled, conflict-free)
        f16x8 af[8];
        #pragma unroll
        for (int kc = 0; kc < 8; ++kc)
            af[kc] = *(const f16x8*)(ldsH[p] + ((rbase + kc * 64 + cbase) ^ rswz));

        // C-init = u_t (bias already folded in by k_embed)
        f32x4 acc[2];
        #pragma unroll
        for (int ct = 0; ct < 2; ++ct)
            #pragma unroll
            for (int rg = 0; rg < 4; ++rg)
                acc[ct][rg] = (float)uv[sel][ct * 4 + rg];

        // prefetch u for t+2 (independent of recurrence)
        {
            const int tt = (t + 2 < TT - 1) ? (t + 2) : (TT - 1);
            #pragma unroll
            for (int ct = 0; ct < 2; ++ct)
                #pragma unroll
                for (int rg = 0; rg < 4; ++rg)
                    uv[sel][ct * 4 + rg] = ub[rg][(size_t)tt * HH + ct * 16];
        }

        // 16 MFMAs: two interleaved 8-deep chains
        #pragma unroll
        for (int kc = 0; kc < 8; ++kc) {
            acc[0] = __builtin_amdgcn_mfma_f32_16x16x32_f16(af[kc], bf[0][kc], acc[0], 0, 0, 0);
            acc[1] = __builtin_amdgcn_mfma_f32_16x16x32_f16(af[kc], bf[1][kc], acc[1], 0, 0, 0);
        }

        // tanh + activity mask -> f16 -> ldsH[p^1] (swizzled)
        char* hw = ldsH[p ^ 1];
        #pragma unroll
        for (int ct = 0; ct < 2; ++ct) {
            const int n2 = (32 * wv + 16 * ct + l15) * 2;
            #pragma unroll
            for (int rg = 0; rg < 4; ++rg) {
                const int m = quad * 4 + rg;
                const float hv = (t >= start[rg]) ? fast_tanh(acc[ct][rg]) : 0.f;
                *(_Float16*)(hw + ((m * 512 + n2) ^ ((m & 7) << 4))) = (_Float16)hv;
            }
        }
        __syncthreads();
        p ^= 1; sel ^= 1;
    }

    // ---- head: H1 = relu(h @ W0^T + b0), 16x1024, via MFMA ----
    {
        f16x8 af[8];
        #pragma unroll
        for (int kc = 0; kc < 8; ++kc)
            af[kc] = *(const f16x8*)(ldsH[p] + ((rbase + kc * 64 + cbase) ^ rswz));

        #pragma unroll
        for (int j = 0; j < 8; ++j) {
            const int n = 128 * wv + 16 * j + l15;
            const float bias = b0[n];
            f32x4 acc = (f32x4){bias, bias, bias, bias};
            const float* wp = W0 + (size_t)n * HH;
            #pragma unroll
            for (int kc = 0; kc < 8; ++kc) {
                const float4* pp = (const float4*)(wp + 32 * kc + 8 * quad);
                f16x8 bw = pack8(pp[0], pp[1]);
                acc = __builtin_amdgcn_mfma_f32_16x16x32_f16(af[kc], bw, acc, 0, 0, 0);
            }
            #pragma unroll
            for (int rg = 0; rg < 4; ++rg) {
                const int m = quad * 4 + rg;
                *(_Float16*)(ldsH1 + ((m * 2048 + n * 2) ^ ((m & 7) << 4)))
                    = (_Float16)fmaxf(acc[rg], 0.f);
            }
        }
    }
    __syncthreads();

    // ---- W1 (1024->5) + relu + log_softmax on VALU ----
    {
        const int m  = tid >> 5;          // batch row 0..15
        const int sl = tid & 31;          // 32-lane k-split
        float pc[CC] = {0.f, 0.f, 0.f, 0.f, 0.f};
        #pragma unroll
        for (int z = 0; z < 4; ++z) {
            const int kb = sl * 64 + z * 16;   // byte offset of 8 f16
            f16x8 hv8 = *(const f16x8*)(ldsH1 + ((m * 2048 + kb) ^ ((m & 7) << 4)));
            float he[8];
            #pragma unroll
            for (int e = 0; e < 8; ++e) he[e] = (float)hv8[e];
            #pragma unroll
            for (int c = 0; c < CC; ++c) {
                const float* w1p = W1 + (size_t)c * MM + sl * 32 + z * 8;
                float4 wa = ((const float4*)w1p)[0];
                float4 wb = ((const float4*)w1p)[1];
                pc[c] += he[0] * wa.x + he[1] * wa.y + he[2] * wa.z + he[3] * wa.w
                       + he[4] * wb.x + he[5] * wb.y + he[6] * wb.z + he[7] * wb.w;
            }
        }
        #pragma unroll
        for (int c = 0; c < CC; ++c) {
            #pragma unroll
            for (int off = 16; off > 0; off >>= 1)
                pc[c] += __shfl_down(pc[c], off, 32);
        }
        if (sl == 0) {
            float v[CC];
            float mx = -1e30f;
            #pragma unroll
            for (int c = 0; c < CC; ++c) {
                v[c] = fmaxf(pc[c] + b1[c], 0.f);
                mx = fmaxf(mx, v[c]);
            }
            float se = 0.f;
            #pragma unroll
            for (int c = 0; c < CC; ++c) se += __expf(v[c] - mx);
            const float lse = mx + __logf(se);
            #pragma unroll
            for (int c = 0; c < CC; ++c)
                out[(size_t)(bB + m) * CC + c] = v[c] - lse;
        }
    }
}

// ---------------------------------------------------------------------------
extern "C" void kernel_launch(void* const* d_in, const int* in_sizes, int n_in,
                              void* d_out, int out_size, void* d_ws, size_t ws_size,
                              hipStream_t stream) {
    const int*   x       = (const int*)d_in[0];
    const int*   lengths = (const int*)d_in[1];
    const float* emb     = (const float*)d_in[2];
    const float* W_ih    = (const float*)d_in[3];
    const float* W_hh    = (const float*)d_in[4];
    const float* b_ih    = (const float*)d_in[5];
    const float* b_hh    = (const float*)d_in[6];
    const float* W0      = (const float*)d_in[7];
    const float* b0      = (const float*)d_in[8];
    const float* W1      = (const float*)d_in[9];
    const float* b1      = (const float*)d_in[10];
    float* out = (float*)d_out;

    // Workspace: u only — exactly BB*TT*HH*2 = 32 MiB.
    _Float16* u = (_Float16*)d_ws;

    k_embed   <<<(BB * TT) / 32, 256, 0, stream>>>(x, emb, W_ih, b_ih, b_hh, u);
    k_rnn_head<<<BB / 16, 512, 0, stream>>>(lengths, W_hh, u, W0, b0, W1, b1, out);
}

// Round 3
// 649.119 us; speedup vs baseline: 3.5831x; 3.5831x over previous
//
#include <hip/hip_runtime.h>
#include <hip/hip_bf16.h>

#define BB 128
#define TT 512
#define EE 128
#define HH 256
#define MM 1024
#define CC 5

typedef _Float16 h2 __attribute__((ext_vector_type(2)));
typedef __fp16 f16x2 __attribute__((ext_vector_type(2)));
typedef __fp16 f16x8 __attribute__((ext_vector_type(8)));
typedef float  f32x4 __attribute__((ext_vector_type(4)));

__device__ inline h2 mkh2(float a, float b) {
    return __builtin_bit_cast(h2, __builtin_amdgcn_cvt_pkrtz(a, b));
}

// pack 8 f32 -> 8 f16 (one MFMA operand fragment)
__device__ inline f16x8 pack8(float4 lo, float4 hi) {
    union { f16x2 h[4]; f16x8 v; } u;
    u.h[0] = __builtin_amdgcn_cvt_pkrtz(lo.x, lo.y);
    u.h[1] = __builtin_amdgcn_cvt_pkrtz(lo.z, lo.w);
    u.h[2] = __builtin_amdgcn_cvt_pkrtz(hi.x, hi.y);
    u.h[3] = __builtin_amdgcn_cvt_pkrtz(hi.z, hi.w);
    return u.v;
}

__device__ inline float fast_tanh(float x) {
    float e = __expf(2.0f * x);
    return 1.0f - 2.0f / (e + 1.0f);
}

// ---------------------------------------------------------------------------
// K1 (MFMA GEMM): u[tok][ch] = bias[ch] + emb[x[tok]] @ W_ih^T, f16 out.
// (unchanged — verified)
// Layouts (m89/m120-verified): A[m=lane&15][k=quad*8+j],
// B[k=quad*8+j][n=lane&15], D col=lane&15 row=quad*4+reg.
// ---------------------------------------------------------------------------
__global__ __launch_bounds__(256, 2)
void k_embed(const int* __restrict__ x,
             const float* __restrict__ emb, const float* __restrict__ W_ih,
             const float* __restrict__ b_ih, const float* __restrict__ b_hh,
             _Float16* __restrict__ u)
{
    const int tb   = blockIdx.x;        // 32-token tile
    const int tid  = threadIdx.x;
    const int wv   = tid >> 6;
    const int lane = tid & 63;
    const int l15  = lane & 15;
    const int quad = lane >> 4;

    __shared__ __align__(16) char ldsA[32 * 256];   // 8KB f16 A-stage
    __shared__ __align__(16) char ldsO[32 * 512];   // 16KB f16 output tile

    f16x8 bf[4][4];
    float bias[4];
    #pragma unroll
    for (int ct = 0; ct < 4; ++ct) {
        const int n = 64 * wv + 16 * ct + l15;
        const float* wp = W_ih + (size_t)n * EE;
        #pragma unroll
        for (int kc = 0; kc < 4; ++kc) {
            const float4* p = (const float4*)(wp + 32 * kc + 8 * quad);
            bf[ct][kc] = pack8(p[0], p[1]);
        }
        bias[ct] = b_ih[n] + b_hh[n];
    }

    {
        const int r = tid >> 3;          // row 0..31
        const int s = tid & 7;           // 16-float segment
        const int tok = x[tb * 32 + r];
        const float4* ep = (const float4*)(emb + (size_t)tok * EE + 16 * s);
        float4 a = ep[0], b = ep[1], c = ep[2], d = ep[3];
        *(f16x8*)(ldsA + r * 256 + 32 * s)      = pack8(a, b);
        *(f16x8*)(ldsA + r * 256 + 32 * s + 16) = pack8(c, d);
    }
    __syncthreads();

    f32x4 acc[2][4];
    #pragma unroll
    for (int rt = 0; rt < 2; ++rt)
        #pragma unroll
        for (int ct = 0; ct < 4; ++ct)
            acc[rt][ct] = (f32x4){bias[ct], bias[ct], bias[ct], bias[ct]};

    #pragma unroll
    for (int kc = 0; kc < 4; ++kc) {
        const int ko = (32 * kc + 8 * quad) * 2;
        f16x8 a0 = *(const f16x8*)(ldsA + (l15)      * 256 + ko);
        f16x8 a1 = *(const f16x8*)(ldsA + (16 + l15) * 256 + ko);
        #pragma unroll
        for (int ct = 0; ct < 4; ++ct) {
            acc[0][ct] = __builtin_amdgcn_mfma_f32_16x16x32_f16(a0, bf[ct][kc], acc[0][ct], 0, 0, 0);
            acc[1][ct] = __builtin_amdgcn_mfma_f32_16x16x32_f16(a1, bf[ct][kc], acc[1][ct], 0, 0, 0);
        }
    }

    #pragma unroll
    for (int rt = 0; rt < 2; ++rt) {
        #pragma unroll
        for (int ct = 0; ct < 4; ++ct) {
            const int chb = (64 * wv + 16 * ct + l15) * 2;
            #pragma unroll
            for (int rg = 0; rg < 4; ++rg) {
                const int tok = 16 * rt + 4 * quad + rg;
                *(_Float16*)(ldsO + tok * 512 + chb) = (_Float16)acc[rt][ct][rg];
            }
        }
    }
    __syncthreads();

    {
        char* dst = (char*)u + (size_t)tb * 16384 + tid * 64;
        const char* src = ldsO + tid * 64;
        #pragma unroll
        for (int q = 0; q < 4; ++q)
            *(float4*)(dst + 16 * q) = *(const float4*)(src + 16 * q);
    }
}

// ---------------------------------------------------------------------------
// K2 (R9): batched MFMA scan, scratch-free + counted-wait barrier.
// 8 blocks x 512 thr; block owns 16 batch rows; per step
// H[16][256] = tanh(U_t + H @ W_hh^T) via 16 MFMAs/wave (2 interleaved
// 8-chains), W_hh B-frags resident (64 VGPR).
// R9 fixes vs R8 (2297us, rule-#20 scratch disaster):
//  - NO runtime-indexed register arrays: t-loop unrolled x2 with NAMED
//    prefetch buffers uvA/uvB and fixed ldsHA<->ldsHB ping-pong.
//  - hot-loop barrier is raw `s_waitcnt lgkmcnt(0); s_barrier` (LDS-only
//    dependency) — no vmcnt(0) drain, so the 2-step-deep u prefetch stays
//    in flight across barriers (compiler inserts counted vmcnt for uv regs).
//  - 32-bit byte offsets for u gather (uniform t*512 scalar).
// t0 rounded down to even: leading extra steps write exact 0 (all rows
// inactive) — harmless. After the loop state is always in ldsHA.
// ---------------------------------------------------------------------------
__global__ __launch_bounds__(512, 1)
void k_rnn_head(const int* __restrict__ lengths, const float* __restrict__ W_hh,
                const _Float16* __restrict__ u,
                const float* __restrict__ W0, const float* __restrict__ b0,
                const float* __restrict__ W1, const float* __restrict__ b1,
                float* __restrict__ out)
{
    const int bB   = blockIdx.x * 16;     // first batch row of this block
    const int tid  = threadIdx.x;
    const int wv   = tid >> 6;            // wave 0..7 -> channels [32wv,32wv+32)
    const int lane = tid & 63;
    const int l15  = lane & 15;
    const int quad = lane >> 4;

    __shared__ __align__(16) char ldsHA[16 * 512];     // 8KB h[16][256] f16
    __shared__ __align__(16) char ldsHB[16 * 512];     // 8KB ping-pong
    __shared__ __align__(16) char ldsH1[16 * 2048];    // 32KB relu(h@W0^T) f16
    __shared__ int slen[16];

    if (tid < 16) slen[tid] = lengths[bB + tid];

    // W_hh B-frags: bf[ct][kc], n = 32*wv + 16*ct + l15, k = 32*kc+8*quad+j
    f16x8 bf[2][8];
    #pragma unroll
    for (int ct = 0; ct < 2; ++ct) {
        const int n = 32 * wv + 16 * ct + l15;
        const float* wp = W_hh + (size_t)n * HH;
        #pragma unroll
        for (int kc = 0; kc < 8; ++kc) {
            const float4* p = (const float4*)(wp + 32 * kc + 8 * quad);
            bf[ct][kc] = pack8(p[0], p[1]);
        }
    }

    // zero h buffer A (512 threads x 16B = 8KB)
    ((float4*)ldsHA)[tid] = (float4){0.f, 0.f, 0.f, 0.f};
    __syncthreads();

    int maxlen = 0;
    #pragma unroll
    for (int i = 0; i < 16; ++i) maxlen = max(maxlen, slen[i]);
    int start[4];
    #pragma unroll
    for (int rg = 0; rg < 4; ++rg) {
        int L = slen[quad * 4 + rg];
        start[rg] = (L >= TT) ? 0 : (TT - L);
    }
    const int t0 = (TT - maxlen) & ~1;    // even-aligned start

    // u gather: 32-bit byte offsets. row m = quad*4+rg, ch base 32wv+l15.
    const char* ubytes = (const char*)u;
    int ubase[4];
    #pragma unroll
    for (int rg = 0; rg < 4; ++rg)
        ubase[rg] = ((bB + quad * 4 + rg) * TT) * (HH * 2);
    const int cb = (32 * wv + l15) * 2;

    _Float16 uvA[8], uvB[8];              // compile-time indexed ONLY

#define ULOAD(DST, T_) {                                                     \
        const int o_ = (((T_) < TT - 1) ? (T_) : (TT - 1)) * (HH * 2);       \
        _Pragma("unroll")                                                    \
        for (int ct_ = 0; ct_ < 2; ++ct_) {                                  \
            _Pragma("unroll")                                                \
            for (int rg_ = 0; rg_ < 4; ++rg_)                                \
                DST[ct_ * 4 + rg_] = *(const _Float16*)(ubytes +             \
                    ubase[rg_] + o_ + cb + ct_ * 32);                        \
        }                                                                    \
    }

    ULOAD(uvA, t0);
    ULOAD(uvB, t0 + 1);

    const int rbase = l15 * 512;          // A row = batch = l15
    const int rswz  = (l15 & 7) << 4;     // G4 XOR swizzle
    const int cbase = quad * 16;          // byte offset of 8-f16 k-slice

#define RSTEP(SRC, DST, UV, T_) {                                            \
        f16x8 af_[8];                                                        \
        _Pragma("unroll")                                                    \
        for (int kc_ = 0; kc_ < 8; ++kc_)                                    \
            af_[kc_] = *(const f16x8*)(SRC +                                 \
                ((rbase + kc_ * 64 + cbase) ^ rswz));                        \
        f32x4 ac0_, ac1_;                                                    \
        _Pragma("unroll")                                                    \
        for (int rg_ = 0; rg_ < 4; ++rg_) {                                  \
            ac0_[rg_] = (float)UV[rg_];                                      \
            ac1_[rg_] = (float)UV[4 + rg_];                                  \
        }                                                                    \
        ULOAD(UV, (T_) + 2);              /* refill, consumed 2 steps on */  \
        _Pragma("unroll")                                                    \
        for (int kc_ = 0; kc_ < 8; ++kc_) {                                  \
            ac0_ = __builtin_amdgcn_mfma_f32_16x16x32_f16(af_[kc_],          \
                       bf[0][kc_], ac0_, 0, 0, 0);                           \
            ac1_ = __builtin_amdgcn_mfma_f32_16x16x32_f16(af_[kc_],          \
                       bf[1][kc_], ac1_, 0, 0, 0);                           \
        }                                                                    \
        _Pragma("unroll")                                                    \
        for (int rg_ = 0; rg_ < 4; ++rg_) {                                  \
            const int m_ = quad * 4 + rg_;                                   \
            const int sw_ = (m_ & 7) << 4;                                   \
            const float h0_ = ((T_) >= start[rg_]) ? fast_tanh(ac0_[rg_])    \
                                                   : 0.f;                    \
            const float h1_ = ((T_) >= start[rg_]) ? fast_tanh(ac1_[rg_])    \
                                                   : 0.f;                    \
            *(_Float16*)(DST + ((m_ * 512 + (32 * wv      + l15) * 2) ^ sw_))\
                = (_Float16)h0_;                                             \
            *(_Float16*)(DST + ((m_ * 512 + (32 * wv + 16 + l15) * 2) ^ sw_))\
                = (_Float16)h1_;                                             \
        }                                                                    \
        asm volatile("s_waitcnt lgkmcnt(0)\n\ts_barrier" ::: "memory");      \
    }

    for (int t = t0; t < TT; t += 2) {
        RSTEP(ldsHA, ldsHB, uvA, t);      // even: A -> B
        RSTEP(ldsHB, ldsHA, uvB, t + 1);  // odd:  B -> A
    }
    // final h state is in ldsHA (even # of steps; zeroed A if no steps)

    // ---- head: H1 = relu(h @ W0^T + b0), 16x1024, via MFMA ----
    {
        f16x8 af[8];
        #pragma unroll
        for (int kc = 0; kc < 8; ++kc)
            af[kc] = *(const f16x8*)(ldsHA + ((rbase + kc * 64 + cbase) ^ rswz));

        #pragma unroll
        for (int j = 0; j < 8; ++j) {
            const int n = 128 * wv + 16 * j + l15;
            const float bias = b0[n];
            f32x4 acc = (f32x4){bias, bias, bias, bias};
            const float* wp = W0 + (size_t)n * HH;
            #pragma unroll
            for (int kc = 0; kc < 8; ++kc) {
                const float4* pp = (const float4*)(wp + 32 * kc + 8 * quad);
                f16x8 bw = pack8(pp[0], pp[1]);
                acc = __builtin_amdgcn_mfma_f32_16x16x32_f16(af[kc], bw, acc, 0, 0, 0);
            }
            #pragma unroll
            for (int rg = 0; rg < 4; ++rg) {
                const int m = quad * 4 + rg;
                *(_Float16*)(ldsH1 + ((m * 2048 + n * 2) ^ ((m & 7) << 4)))
                    = (_Float16)fmaxf(acc[rg], 0.f);
            }
        }
    }
    __syncthreads();

    // ---- W1 (1024->5) + relu + log_softmax on VALU ----
    {
        const int m  = tid >> 5;          // batch row 0..15
        const int sl = tid & 31;          // 32-lane k-split
        float pc[CC] = {0.f, 0.f, 0.f, 0.f, 0.f};
        #pragma unroll
        for (int z = 0; z < 4; ++z) {
            const int kb = sl * 64 + z * 16;   // byte offset of 8 f16
            f16x8 hv8 = *(const f16x8*)(ldsH1 + ((m * 2048 + kb) ^ ((m & 7) << 4)));
            float he[8];
            #pragma unroll
            for (int e = 0; e < 8; ++e) he[e] = (float)hv8[e];
            #pragma unroll
            for (int c = 0; c < CC; ++c) {
                const float* w1p = W1 + (size_t)c * MM + sl * 32 + z * 8;
                float4 wa = ((const float4*)w1p)[0];
                float4 wb = ((const float4*)w1p)[1];
                pc[c] += he[0] * wa.x + he[1] * wa.y + he[2] * wa.z + he[3] * wa.w
                       + he[4] * wb.x + he[5] * wb.y + he[6] * wb.z + he[7] * wb.w;
            }
        }
        #pragma unroll
        for (int c = 0; c < CC; ++c) {
            #pragma unroll
            for (int off = 16; off > 0; off >>= 1)
                pc[c] += __shfl_down(pc[c], off, 32);
        }
        if (sl == 0) {
            float v[CC];
            float mx = -1e30f;
            #pragma unroll
            for (int c = 0; c < CC; ++c) {
                v[c] = fmaxf(pc[c] + b1[c], 0.f);
                mx = fmaxf(mx, v[c]);
            }
            float se = 0.f;
            #pragma unroll
            for (int c = 0; c < CC; ++c) se += __expf(v[c] - mx);
            const float lse = mx + __logf(se);
            #pragma unroll
            for (int c = 0; c < CC; ++c)
                out[(size_t)(bB + m) * CC + c] = v[c] - lse;
        }
    }
}

// ---------------------------------------------------------------------------
extern "C" void kernel_launch(void* const* d_in, const int* in_sizes, int n_in,
                              void* d_out, int out_size, void* d_ws, size_t ws_size,
                              hipStream_t stream) {
    const int*   x       = (const int*)d_in[0];
    const int*   lengths = (const int*)d_in[1];
    const float* emb     = (const float*)d_in[2];
    const float* W_ih    = (const float*)d_in[3];
    const float* W_hh    = (const float*)d_in[4];
    const float* b_ih    = (const float*)d_in[5];
    const float* b_hh    = (const float*)d_in[6];
    const float* W0      = (const float*)d_in[7];
    const float* b0      = (const float*)d_in[8];
    const float* W1      = (const float*)d_in[9];
    const float* b1      = (const float*)d_in[10];
    float* out = (float*)d_out;

    // Workspace: u only — exactly BB*TT*HH*2 = 32 MiB.
    _Float16* u = (_Float16*)d_ws;

    k_embed   <<<(BB * TT) / 32, 256, 0, stream>>>(x, emb, W_ih, b_ih, b_hh, u);
    k_rnn_head<<<BB / 16, 512, 0, stream>>>(lengths, W_hh, u, W0, b0, W1, b1, out);
}

// Round 4
// 638.056 us; speedup vs baseline: 3.6452x; 1.0173x over previous
//
#include <hip/hip_runtime.h>
#include <hip/hip_bf16.h>

#define BB 128
#define TT 512
#define EE 128
#define HH 256
#define MM 1024
#define CC 5

typedef _Float16 h2 __attribute__((ext_vector_type(2)));
typedef __fp16 f16x2 __attribute__((ext_vector_type(2)));
typedef __fp16 f16x8 __attribute__((ext_vector_type(8)));
typedef float  f32x4 __attribute__((ext_vector_type(4)));

__device__ inline h2 mkh2(float a, float b) {
    return __builtin_bit_cast(h2, __builtin_amdgcn_cvt_pkrtz(a, b));
}

// pack 8 f32 -> 8 f16 (one MFMA operand fragment)
__device__ inline f16x8 pack8(float4 lo, float4 hi) {
    union { f16x2 h[4]; f16x8 v; } u;
    u.h[0] = __builtin_amdgcn_cvt_pkrtz(lo.x, lo.y);
    u.h[1] = __builtin_amdgcn_cvt_pkrtz(lo.z, lo.w);
    u.h[2] = __builtin_amdgcn_cvt_pkrtz(hi.x, hi.y);
    u.h[3] = __builtin_amdgcn_cvt_pkrtz(hi.z, hi.w);
    return u.v;
}

// 5-instr tanh: e = 2^(x*2*log2e); 1 - 2/(e+1)
__device__ inline float fast_tanh(float x) {
    float e = __builtin_amdgcn_exp2f(x * 2.8853900817779268f);
    return 1.0f - 2.0f / (e + 1.0f);
}

// bijective LDS swizzle for H tiles: conflict-free on both b128 reads
// (row varies per lane, 16B col slices) and b16 writes (4 rows x 32B spans).
#define SWZ(m) ((((m) & 7) << 4) ^ (((m) & 8) << 2))

// ---------------------------------------------------------------------------
// K1 (MFMA GEMM): u[tok][ch] = bias[ch] + emb[x[tok]] @ W_ih^T, f16 out.
// R10: early-exit for fully-inactive 32-token tiles (t_end < T - len[b]) —
// k_rnn masks those steps, so garbage u there is never consumed (~50% skip).
// Layouts (m89/m120-verified): A[m=lane&15][k=quad*8+j],
// B[k=quad*8+j][n=lane&15], D col=lane&15 row=quad*4+reg.
// ---------------------------------------------------------------------------
__global__ __launch_bounds__(256, 2)
void k_embed(const int* __restrict__ x, const int* __restrict__ lengths,
             const float* __restrict__ emb, const float* __restrict__ W_ih,
             const float* __restrict__ b_ih, const float* __restrict__ b_hh,
             _Float16* __restrict__ u)
{
    const int tb   = blockIdx.x;        // 32-token tile
    // tile covers batch row b = tb/16, t in [(tb%16)*32, +32)
    {
        const int bb   = tb >> 4;
        const int tend = ((tb & 15) << 5) + 31;
        if (tend < TT - lengths[bb]) return;   // fully inactive -> skip
    }
    const int tid  = threadIdx.x;
    const int wv   = tid >> 6;
    const int lane = tid & 63;
    const int l15  = lane & 15;
    const int quad = lane >> 4;

    __shared__ __align__(16) char ldsA[32 * 256];   // 8KB f16 A-stage
    __shared__ __align__(16) char ldsO[32 * 512];   // 16KB f16 output tile

    f16x8 bf[4][4];
    float bias[4];
    #pragma unroll
    for (int ct = 0; ct < 4; ++ct) {
        const int n = 64 * wv + 16 * ct + l15;
        const float* wp = W_ih + (size_t)n * EE;
        #pragma unroll
        for (int kc = 0; kc < 4; ++kc) {
            const float4* p = (const float4*)(wp + 32 * kc + 8 * quad);
            bf[ct][kc] = pack8(p[0], p[1]);
        }
        bias[ct] = b_ih[n] + b_hh[n];
    }

    {
        const int r = tid >> 3;          // row 0..31
        const int s = tid & 7;           // 16-float segment
        const int tok = x[tb * 32 + r];
        const float4* ep = (const float4*)(emb + (size_t)tok * EE + 16 * s);
        float4 a = ep[0], b = ep[1], c = ep[2], d = ep[3];
        *(f16x8*)(ldsA + r * 256 + 32 * s)      = pack8(a, b);
        *(f16x8*)(ldsA + r * 256 + 32 * s + 16) = pack8(c, d);
    }
    __syncthreads();

    f32x4 acc[2][4];
    #pragma unroll
    for (int rt = 0; rt < 2; ++rt)
        #pragma unroll
        for (int ct = 0; ct < 4; ++ct)
            acc[rt][ct] = (f32x4){bias[ct], bias[ct], bias[ct], bias[ct]};

    #pragma unroll
    for (int kc = 0; kc < 4; ++kc) {
        const int ko = (32 * kc + 8 * quad) * 2;
        f16x8 a0 = *(const f16x8*)(ldsA + (l15)      * 256 + ko);
        f16x8 a1 = *(const f16x8*)(ldsA + (16 + l15) * 256 + ko);
        #pragma unroll
        for (int ct = 0; ct < 4; ++ct) {
            acc[0][ct] = __builtin_amdgcn_mfma_f32_16x16x32_f16(a0, bf[ct][kc], acc[0][ct], 0, 0, 0);
            acc[1][ct] = __builtin_amdgcn_mfma_f32_16x16x32_f16(a1, bf[ct][kc], acc[1][ct], 0, 0, 0);
        }
    }

    #pragma unroll
    for (int rt = 0; rt < 2; ++rt) {
        #pragma unroll
        for (int ct = 0; ct < 4; ++ct) {
            const int chb = (64 * wv + 16 * ct + l15) * 2;
            #pragma unroll
            for (int rg = 0; rg < 4; ++rg) {
                const int tok = 16 * rt + 4 * quad + rg;
                *(_Float16*)(ldsO + tok * 512 + chb) = (_Float16)acc[rt][ct][rg];
            }
        }
    }
    __syncthreads();

    {
        char* dst = (char*)u + (size_t)tb * 16384 + tid * 64;
        const char* src = ldsO + tid * 64;
        #pragma unroll
        for (int q = 0; q < 4; ++q)
            *(float4*)(dst + 16 * q) = *(const float4*)(src + 16 * q);
    }
}

// ---------------------------------------------------------------------------
// K2 (R10): batched MFMA scan. 8 blocks x 512 thr; block owns 16 batch rows;
// per step H[16][256] = tanh(U_t + H @ W_hh^T), 16 MFMA/wave, W_hh B-frags
// resident. Fixes vs R9 (505us, ~2400cyc/step):
//  - barrier is sched_barrier(0) + asm lgkmcnt(0) (NO memory clobber) +
//    __builtin_amdgcn_s_barrier() + sched_barrier(0). R9's "memory" clobber
//    made SIInsertWaitcnts drain vmcnt(0) every step -> u-prefetch
//    serialized -> full gather latency per step.
//  - all LDS read/write offsets hoisted to loop-invariant VGPRs (rdoff[8],
//    wroff[8]); u gather = uniform SGPR base (readfirstlane(t*512)) + 8
//    invariant voffsets. Per-step addressing VALU ~0.
//  - SWZ(m) = ((m&7)<<4)^((m&8)<<2): conflict-free reads AND writes
//    (old swizzle collided rows m, m+8 on writes -> 950K conflicts).
// ---------------------------------------------------------------------------
__global__ __launch_bounds__(512, 1)
void k_rnn_head(const int* __restrict__ lengths, const float* __restrict__ W_hh,
                const _Float16* __restrict__ u,
                const float* __restrict__ W0, const float* __restrict__ b0,
                const float* __restrict__ W1, const float* __restrict__ b1,
                float* __restrict__ out)
{
    const int bB   = blockIdx.x * 16;     // first batch row of this block
    const int tid  = threadIdx.x;
    const int wv   = tid >> 6;            // wave 0..7 -> channels [32wv,32wv+32)
    const int lane = tid & 63;
    const int l15  = lane & 15;
    const int quad = lane >> 4;

    __shared__ __align__(16) char ldsHA[16 * 512];     // 8KB h[16][256] f16
    __shared__ __align__(16) char ldsHB[16 * 512];     // 8KB ping-pong
    __shared__ __align__(16) char ldsH1[16 * 2048];    // 32KB relu(h@W0^T) f16
    __shared__ int slen[16];

    if (tid < 16) slen[tid] = lengths[bB + tid];

    // W_hh B-frags: bf[ct][kc], n = 32*wv + 16*ct + l15, k = 32*kc+8*quad+j
    f16x8 bf[2][8];
    #pragma unroll
    for (int ct = 0; ct < 2; ++ct) {
        const int n = 32 * wv + 16 * ct + l15;
        const float* wp = W_hh + (size_t)n * HH;
        #pragma unroll
        for (int kc = 0; kc < 8; ++kc) {
            const float4* p = (const float4*)(wp + 32 * kc + 8 * quad);
            bf[ct][kc] = pack8(p[0], p[1]);
        }
    }

    // zero h buffer A
    ((float4*)ldsHA)[tid] = (float4){0.f, 0.f, 0.f, 0.f};
    __syncthreads();

    int maxlen = 0;
    #pragma unroll
    for (int i = 0; i < 16; ++i) maxlen = max(maxlen, slen[i]);
    int start[4];
    #pragma unroll
    for (int rg = 0; rg < 4; ++rg) {
        int L = slen[quad * 4 + rg];
        start[rg] = (L >= TT) ? 0 : (TT - L);
    }
    const int t0 = (TT - maxlen) & ~1;    // even-aligned start

    // ---- loop-invariant offsets (all compile-time-indexed -> registers) ----
    int rdoff[8];                          // A-frag reads: row l15, 16B slices
    #pragma unroll
    for (int kc = 0; kc < 8; ++kc)
        rdoff[kc] = (l15 * 512 + kc * 64 + quad * 16) ^ SWZ(l15);

    int wroff[8];                          // h writes: [ct*4+rg]
    #pragma unroll
    for (int ct = 0; ct < 2; ++ct)
        #pragma unroll
        for (int rg = 0; rg < 4; ++rg) {
            const int m = quad * 4 + rg;
            wroff[ct * 4 + rg] = (m * 512 + (32 * wv + 16 * ct + l15) * 2) ^ SWZ(m);
        }

    int uvoffs[8];                         // u gather voffsets: [ct*4+rg]
    #pragma unroll
    for (int i = 0; i < 8; ++i)
        uvoffs[i] = (bB + quad * 4 + (i & 3)) * (TT * HH * 2)
                  + (32 * wv + l15) * 2 + (i >> 2) * 32;

    const char* ubytes = (const char*)u;
    _Float16 uvA[8], uvB[8];               // compile-time indexed ONLY

#define ULOAD(DST, T_) {                                                     \
        const int tcl_ = ((T_) < TT - 1) ? (T_) : (TT - 1);                  \
        const char* up_ = ubytes +                                           \
            (size_t)(unsigned)__builtin_amdgcn_readfirstlane(tcl_ << 9);     \
        _Pragma("unroll")                                                    \
        for (int i_ = 0; i_ < 8; ++i_)                                       \
            DST[i_] = *(const _Float16*)(up_ + uvoffs[i_]);                  \
    }

    ULOAD(uvA, t0);
    ULOAD(uvB, t0 + 1);

#define RSTEP(SRC, DST, UV, T_) {                                            \
        f16x8 af_[8];                                                        \
        _Pragma("unroll")                                                    \
        for (int kc_ = 0; kc_ < 8; ++kc_)                                    \
            af_[kc_] = *(const f16x8*)(SRC + rdoff[kc_]);                    \
        f32x4 ac0_, ac1_;                                                    \
        _Pragma("unroll")                                                    \
        for (int rg_ = 0; rg_ < 4; ++rg_) {                                  \
            ac0_[rg_] = (float)UV[rg_];                                      \
            ac1_[rg_] = (float)UV[4 + rg_];                                  \
        }                                                                    \
        ULOAD(UV, (T_) + 2);              /* refill, consumed 2 steps on */  \
        _Pragma("unroll")                                                    \
        for (int kc_ = 0; kc_ < 8; ++kc_) {                                  \
            ac0_ = __builtin_amdgcn_mfma_f32_16x16x32_f16(af_[kc_],          \
                       bf[0][kc_], ac0_, 0, 0, 0);                           \
            ac1_ = __builtin_amdgcn_mfma_f32_16x16x32_f16(af_[kc_],          \
                       bf[1][kc_], ac1_, 0, 0, 0);                           \
        }                                                                    \
        _Pragma("unroll")                                                    \
        for (int rg_ = 0; rg_ < 4; ++rg_) {                                  \
            const bool act_ = (T_) >= start[rg_];                            \
            const float h0_ = act_ ? fast_tanh(ac0_[rg_]) : 0.f;             \
            const float h1_ = act_ ? fast_tanh(ac1_[rg_]) : 0.f;             \
            *(_Float16*)(DST + wroff[rg_])     = (_Float16)h0_;              \
            *(_Float16*)(DST + wroff[4 + rg_]) = (_Float16)h1_;              \
        }                                                                    \
        __builtin_amdgcn_sched_barrier(0);                                   \
        asm volatile("s_waitcnt lgkmcnt(0)");                                \
        __builtin_amdgcn_s_barrier();                                        \
        __builtin_amdgcn_sched_barrier(0);                                   \
    }

    for (int t = t0; t < TT; t += 2) {
        RSTEP(ldsHA, ldsHB, uvA, t);      // even: A -> B
        RSTEP(ldsHB, ldsHA, uvB, t + 1);  // odd:  B -> A
    }
    // final h state is in ldsHA (even # of steps; zeroed A if no steps)

    // ---- head: H1 = relu(h @ W0^T + b0), 16x1024, via MFMA ----
    {
        f16x8 af[8];
        #pragma unroll
        for (int kc = 0; kc < 8; ++kc)
            af[kc] = *(const f16x8*)(ldsHA + rdoff[kc]);

        #pragma unroll
        for (int j = 0; j < 8; ++j) {
            const int n = 128 * wv + 16 * j + l15;
            const float bias = b0[n];
            f32x4 acc = (f32x4){bias, bias, bias, bias};
            const float* wp = W0 + (size_t)n * HH;
            #pragma unroll
            for (int kc = 0; kc < 8; ++kc) {
                const float4* pp = (const float4*)(wp + 32 * kc + 8 * quad);
                f16x8 bw = pack8(pp[0], pp[1]);
                acc = __builtin_amdgcn_mfma_f32_16x16x32_f16(af[kc], bw, acc, 0, 0, 0);
            }
            #pragma unroll
            for (int rg = 0; rg < 4; ++rg) {
                const int m = quad * 4 + rg;
                *(_Float16*)(ldsH1 + ((m * 2048 + n * 2) ^ ((m & 7) << 4)))
                    = (_Float16)fmaxf(acc[rg], 0.f);
            }
        }
    }
    __syncthreads();

    // ---- W1 (1024->5) + relu + log_softmax on VALU ----
    {
        const int m  = tid >> 5;          // batch row 0..15
        const int sl = tid & 31;          // 32-lane k-split
        float pc[CC] = {0.f, 0.f, 0.f, 0.f, 0.f};
        #pragma unroll
        for (int z = 0; z < 4; ++z) {
            const int kb = sl * 64 + z * 16;   // byte offset of 8 f16
            f16x8 hv8 = *(const f16x8*)(ldsH1 + ((m * 2048 + kb) ^ ((m & 7) << 4)));
            float he[8];
            #pragma unroll
            for (int e = 0; e < 8; ++e) he[e] = (float)hv8[e];
            #pragma unroll
            for (int c = 0; c < CC; ++c) {
                const float* w1p = W1 + (size_t)c * MM + sl * 32 + z * 8;
                float4 wa = ((const float4*)w1p)[0];
                float4 wb = ((const float4*)w1p)[1];
                pc[c] += he[0] * wa.x + he[1] * wa.y + he[2] * wa.z + he[3] * wa.w
                       + he[4] * wb.x + he[5] * wb.y + he[6] * wb.z + he[7] * wb.w;
            }
        }
        #pragma unroll
        for (int c = 0; c < CC; ++c) {
            #pragma unroll
            for (int off = 16; off > 0; off >>= 1)
                pc[c] += __shfl_down(pc[c], off, 32);
        }
        if (sl == 0) {
            float v[CC];
            float mx = -1e30f;
            #pragma unroll
            for (int c = 0; c < CC; ++c) {
                v[c] = fmaxf(pc[c] + b1[c], 0.f);
                mx = fmaxf(mx, v[c]);
            }
            float se = 0.f;
            #pragma unroll
            for (int c = 0; c < CC; ++c) se += __expf(v[c] - mx);
            const float lse = mx + __logf(se);
            #pragma unroll
            for (int c = 0; c < CC; ++c)
                out[(size_t)(bB + m) * CC + c] = v[c] - lse;
        }
    }
}

// ---------------------------------------------------------------------------
extern "C" void kernel_launch(void* const* d_in, const int* in_sizes, int n_in,
                              void* d_out, int out_size, void* d_ws, size_t ws_size,
                              hipStream_t stream) {
    const int*   x       = (const int*)d_in[0];
    const int*   lengths = (const int*)d_in[1];
    const float* emb     = (const float*)d_in[2];
    const float* W_ih    = (const float*)d_in[3];
    const float* W_hh    = (const float*)d_in[4];
    const float* b_ih    = (const float*)d_in[5];
    const float* b_hh    = (const float*)d_in[6];
    const float* W0      = (const float*)d_in[7];
    const float* b0      = (const float*)d_in[8];
    const float* W1      = (const float*)d_in[9];
    const float* b1      = (const float*)d_in[10];
    float* out = (float*)d_out;

    // Workspace: u only — exactly BB*TT*HH*2 = 32 MiB.
    _Float16* u = (_Float16*)d_ws;

    k_embed   <<<(BB * TT) / 32, 256, 0, stream>>>(x, lengths, emb, W_ih, b_ih, b_hh, u);
    k_rnn_head<<<BB / 16, 512, 0, stream>>>(lengths, W_hh, u, W0, b0, W1, b1, out);
}